// Round 8
// baseline (3573.787 us; speedup 1.0000x reference)
//
#include <hip/hip_runtime.h>
#include <math.h>

#define Bb 4096
#define Mm 306
#define Nn 984      // complex cols
#define NCP 1024    // padded complex cols
#define KA 2048     // w real k-cols (padded)
#define ITERS 50
#define KSQ 9       // squaring stages: G^(2^9) then Rayleigh

typedef _Float16 f16x8 __attribute__((ext_vector_type(8)));
typedef float f32x16 __attribute__((ext_vector_type(16)));

__device__ __forceinline__ void cmac(float2& c, const float2 a, const float2 b) {
    c.x = fmaf(a.x, b.x, c.x);
    c.x = fmaf(-a.y, b.y, c.x);
    c.y = fmaf(a.x, b.y, c.y);
    c.y = fmaf(a.y, b.x, c.y);
}

__device__ __forceinline__ unsigned short f16bits(float v) {
    union { _Float16 h; unsigned short u; } cv;
    cv.h = (_Float16)v;
    return cv.u;
}
__device__ __forceinline__ float f16lo(unsigned int u) {
    union { unsigned short s; _Float16 h; } cv; cv.s = (unsigned short)(u & 0xffffu);
    return (float)cv.h;
}
__device__ __forceinline__ float f16hi(unsigned int u) {
    union { unsigned short s; _Float16 h; } cv; cv.s = (unsigned short)(u >> 16);
    return (float)cv.h;
}

__device__ __forceinline__ void load_lds16(const void* g, void* l) {
    __builtin_amdgcn_global_load_lds((const __attribute__((address_space(1))) void*)g,
                                     (__attribute__((address_space(3))) void*)l, 16, 0, 0);
}

// ---- swizzled uint (4B) index, w/A operand (K=2048: 32 ktiles), (row b, complex col c) --
__device__ __forceinline__ size_t swzA(int b, int c) {
    return ((size_t)(((b >> 7) * 32 + (c >> 5)) * 1024 + ((c >> 2) & 7) * 128 + (b & 127))) * 4 + (c & 3);
}
// ---- B1 operand (phi^T pack, K=2048: 32 ktiles), (row jr, uint col q) ----
__device__ __forceinline__ size_t swzB(int jr, int q) {
    return ((size_t)(((jr >> 7) * 32 + (q >> 5)) * 1024 + ((q >> 2) & 7) * 128 + (jr & 127))) * 4 + (q & 3);
}
// ---- err/A2 operand (K=640: 10 ktiles), (row b, complex col c<320) ----
__device__ __forceinline__ size_t swzA2(int b, int c) {
    return ((size_t)(((b >> 7) * 10 + (c >> 5)) * 1024 + ((c >> 2) & 7) * 128 + (b & 127))) * 4 + (c & 3);
}
// ---- B2 operand (-step*conj(phi) pack, K=640: 10 ktiles), (row jr, uint col q<320) ----
__device__ __forceinline__ size_t swzB2(int jr, int q) {
    return ((size_t)(((jr >> 7) * 10 + (q >> 5)) * 1024 + ((q >> 2) & 7) * 128 + (jr & 127))) * 4 + (q & 3);
}

// ---------------- G = phi * phi^H  (306x306 complex) ----------------
__global__ void gram_kernel(const float* __restrict__ pr, const float* __restrict__ pi,
                            float2* __restrict__ G) {
    int j = blockIdx.x * 16 + threadIdx.x;
    int i = blockIdx.y * 16 + threadIdx.y;
    if (i >= Mm || j >= Mm) return;
    const float* pri = pr + (size_t)i * Nn;
    const float* pii = pi + (size_t)i * Nn;
    const float* prj = pr + (size_t)j * Nn;
    const float* pij = pi + (size_t)j * Nn;
    float ar = 0.f, ai = 0.f;
    for (int n = 0; n < Nn; ++n) {
        float xr = pri[n], xi = pii[n], yr = prj[n], yi = pij[n];
        ar = fmaf(xr, yr, ar); ar = fmaf(xi, yi, ar);
        ai = fmaf(xi, yr, ai); ai = fmaf(-xr, yi, ai);
    }
    G[i * Mm + j] = make_float2(ar, ai);
}

// ---------------- Frobenius^2 reduction ----------------
__global__ void frob_kernel(const float2* __restrict__ H, float* __restrict__ slot, int n) {
    int idx = blockIdx.x * blockDim.x + threadIdx.x;
    int stride = gridDim.x * blockDim.x;
    float s = 0.f;
    for (int i = idx; i < n; i += stride) {
        float2 v = H[i];
        s = fmaf(v.x, v.x, s);
        s = fmaf(v.y, v.y, s);
    }
    #pragma unroll
    for (int o = 32; o > 0; o >>= 1) s += __shfl_down(s, o, 64);
    __shared__ float wsum[4];
    int lane = threadIdx.x & 63, wv = threadIdx.x >> 6;
    if (lane == 0) wsum[wv] = s;
    __syncthreads();
    if (threadIdx.x == 0) atomicAdd(slot, wsum[0] + wsum[1] + wsum[2] + wsum[3]);
}

// ---------------- C += (A/||A||_F)^2 partial (split-K, C pre-zeroed) ----------------
__global__ void sqmm_kernel(const float2* __restrict__ A, float2* __restrict__ C,
                            const float* __restrict__ fslot) {
    __shared__ float2 As[32][33];
    __shared__ float2 Bs[32][33];
    float inv = 1.0f / fslot[0];
    int tx = threadIdx.x, ty = threadIdx.y;
    int t = ty * 16 + tx;
    int r0 = blockIdx.y * 32, c0 = blockIdx.x * 32;
    int zs = blockIdx.z * 80;
    int ze = zs + 80 < Mm ? zs + 80 : Mm;
    float2 acc[2][2] = {};
    for (int k0 = zs; k0 < ze; k0 += 32) {
        #pragma unroll
        for (int i = 0; i < 4; ++i) {
            int idx = t + i * 256;
            int rr = idx >> 5, cc = idx & 31;
            int gr = r0 + rr, gk = k0 + cc;
            As[rr][cc] = (gr < Mm && gk < ze) ? A[gr * Mm + gk] : make_float2(0.f, 0.f);
            int gk2 = k0 + rr, gc = c0 + cc;
            Bs[rr][cc] = (gk2 < ze && gc < Mm) ? A[gk2 * Mm + gc] : make_float2(0.f, 0.f);
        }
        __syncthreads();
        #pragma unroll 8
        for (int kk = 0; kk < 32; ++kk) {
            float2 a0 = As[ty * 2][kk], a1 = As[ty * 2 + 1][kk];
            float2 b0 = Bs[kk][tx * 2], b1 = Bs[kk][tx * 2 + 1];
            cmac(acc[0][0], a0, b0); cmac(acc[0][1], a0, b1);
            cmac(acc[1][0], a1, b0); cmac(acc[1][1], a1, b1);
        }
        __syncthreads();
    }
    #pragma unroll
    for (int i = 0; i < 2; ++i) {
        int gr = r0 + ty * 2 + i;
        #pragma unroll
        for (int j = 0; j < 2; ++j) {
            int gc = c0 + tx * 2 + j;
            if (gr < Mm && gc < Mm) {
                atomicAdd(&C[gr * Mm + gc].x, acc[i][j].x * inv);
                atomicAdd(&C[gr * Mm + gc].y, acc[i][j].y * inv);
            }
        }
    }
}

// ---------------- Rayleigh: lambda = v^H G v / v^H v, v = H*ones ----------------
__global__ void rayleigh_kernel(const float2* __restrict__ H, const float2* __restrict__ G,
                                float* __restrict__ sc) {
    __shared__ float2 v[Mm];
    __shared__ float rn[320], rd[320];
    int t = threadIdx.x;
    if (t < Mm) {
        float2 s = make_float2(0.f, 0.f);
        for (int j = 0; j < Mm; ++j) { float2 h = H[t * Mm + j]; s.x += h.x; s.y += h.y; }
        v[t] = s;
    }
    __syncthreads();
    float num = 0.f, den = 0.f;
    if (t < Mm) {
        float2 u = make_float2(0.f, 0.f);
        for (int k = 0; k < Mm; ++k) {
            float2 g = G[k * Mm + t];
            float2 vk = v[k];
            u.x = fmaf(g.x, vk.x, u.x); u.x = fmaf(g.y, vk.y, u.x);
            u.y = fmaf(g.x, vk.y, u.y); u.y = fmaf(-g.y, vk.x, u.y);
        }
        float2 vt = v[t];
        num = vt.x * u.x + vt.y * u.y;
        den = vt.x * vt.x + vt.y * vt.y;
    }
    rn[t] = num; rd[t] = den;
    __syncthreads();
    if (t == 0) {
        float sn = 0.f, sd = 0.f;
        for (int i = 0; i < 320; ++i) { sn += rn[i]; sd += rd[i]; }
        float lam = sn / sd;
        float step = 1.0f / lam;
        sc[0] = step;
        sc[1] = 0.1f * step;
    }
}

// ---------------- ppack: phi -> B1 (phi^T, f16) and B2 (-step*conj(phi), f16) ----------
// B1 rows jr1 from m: Re=(phiR,-phiI), Im=(phiI,phiR); uint col = n
// B2 rows jr2 from n: Re=(-s*phiR,-s*phiI), Im=(s*phiI,-s*phiR); uint col = m
__global__ void ppack_kernel(const float* __restrict__ pr, const float* __restrict__ pi,
                             unsigned int* __restrict__ B1u, unsigned int* __restrict__ B2u,
                             const float* __restrict__ sc) {
    int n = blockIdx.x * 256 + threadIdx.x;
    int m = blockIdx.y;
    if (n >= Nn) return;
    float xr = pr[(size_t)m * Nn + n], xi = pi[(size_t)m * Nn + n];
    unsigned short a = f16bits(xr), b = f16bits(xi);
    int jr1 = ((m >> 5) * 64) + (m & 31);
    B1u[swzB(jr1, n)]      = (unsigned)a | ((unsigned)(b ^ 0x8000u) << 16);
    B1u[swzB(jr1 + 32, n)] = (unsigned)b | ((unsigned)a << 16);
    float s = sc[0];
    unsigned short x = f16bits(-s * xr), y = f16bits(-s * xi);
    int jr2 = ((n >> 5) * 64) + (n & 31);
    B2u[swzB2(jr2, m)]      = (unsigned)x | ((unsigned)y << 16);
    B2u[swzB2(jr2 + 32, m)] = (unsigned)(y ^ 0x8000u) | ((unsigned)x << 16);
}

// ---------------- rph16[b][c] = f16pair(step * sum_m r[b][m]*conj(phi[m][c])) ----------
__global__ __launch_bounds__(256) void rphi_kernel(
    const float* __restrict__ rr, const float* __restrict__ ri,
    const float* __restrict__ pr, const float* __restrict__ pi,
    unsigned int* __restrict__ rph16, const float* __restrict__ sc) {
    __shared__ float2 As[64][18];
    __shared__ float2 Bs[16][66];
    float step = sc[0];
    int t = threadIdx.x;
    int tx = t & 15, ty = t >> 4;
    int b0 = blockIdx.x * 64, c0 = blockIdx.y * 64;
    float2 acc[4][4] = {};
    for (int k0 = 0; k0 < Mm; k0 += 16) {
        #pragma unroll
        for (int rep = 0; rep < 4; ++rep) {
            int idx = t + rep * 256;
            int row = idx >> 4, kk = idx & 15;
            int gk = k0 + kk;
            float re = 0.f, im = 0.f;
            if (gk < Mm) {
                re = rr[(size_t)(b0 + row) * Mm + gk];
                im = ri[(size_t)(b0 + row) * Mm + gk];
            }
            As[row][kk] = make_float2(re, im);
        }
        {
            int rb = t >> 4, sb = t & 15;
            int gm = k0 + rb, gc = c0 + sb * 4;
            float4 vr = make_float4(0.f, 0.f, 0.f, 0.f), vi = vr;
            if (gm < Mm && gc < Nn) {
                vr = *reinterpret_cast<const float4*>(&pr[(size_t)gm * Nn + gc]);
                vi = *reinterpret_cast<const float4*>(&pi[(size_t)gm * Nn + gc]);
            }
            Bs[rb][sb * 4 + 0] = make_float2(vr.x, -vi.x);
            Bs[rb][sb * 4 + 1] = make_float2(vr.y, -vi.y);
            Bs[rb][sb * 4 + 2] = make_float2(vr.z, -vi.z);
            Bs[rb][sb * 4 + 3] = make_float2(vr.w, -vi.w);
        }
        __syncthreads();
        #pragma unroll
        for (int kk = 0; kk < 16; ++kk) {
            float2 a[4], b[4];
            #pragma unroll
            for (int i = 0; i < 4; ++i) a[i] = As[ty * 4 + i][kk];
            #pragma unroll
            for (int j = 0; j < 4; ++j) b[j] = Bs[kk][tx * 4 + j];
            #pragma unroll
            for (int i = 0; i < 4; ++i)
                #pragma unroll
                for (int j = 0; j < 4; ++j) cmac(acc[i][j], a[i], b[j]);
        }
        __syncthreads();
    }
    #pragma unroll
    for (int i = 0; i < 4; ++i) {
        int gb = b0 + ty * 4 + i;
        #pragma unroll
        for (int j = 0; j < 4; ++j) {
            int gc = c0 + tx * 4 + j;
            rph16[(size_t)gb * NCP + gc] =
                (unsigned)f16bits(step * acc[i][j].x) | ((unsigned)f16bits(step * acc[i][j].y) << 16);
        }
    }
}

// ---------------- GEMM1: e'[b][m] = sum_n w[b][n]*phi[m][n]  (K=2048, grid 32x5) --------
__global__ __launch_bounds__(256, 2) void gemm_e_kernel(
    const _Float16* __restrict__ wfi, const _Float16* __restrict__ B1,
    unsigned int* __restrict__ errU) {
    __shared__ _Float16 As[8192];
    __shared__ _Float16 Bs[8192];
    int tid = threadIdx.x;
    int lane = tid & 63, wv = tid >> 6;
    int wm = wv & 1, wn = wv >> 1;
    int bblk = blockIdx.x, nblk = blockIdx.y;
    int l31 = lane & 31, lh = lane >> 5;

    f32x16 acc[2][2] = {};

    for (int kt = 0; kt < 32; ++kt) {
        #pragma unroll
        for (int c = 0; c < 4; ++c) {
            int u = c * 256 + tid;
            const char* ga = (const char*)wfi + (((size_t)(bblk * 32 + kt)) * 1024 + u) * 16;
            load_lds16(ga, &As[(size_t)(c * 256 + wv * 64) * 8]);
            const char* gb = (const char*)B1 + (((size_t)(nblk * 32 + kt)) * 1024 + u) * 16;
            load_lds16(gb, &Bs[(size_t)(c * 256 + wv * 64) * 8]);
        }
        __syncthreads();
        #pragma unroll
        for (int s = 0; s < 4; ++s) {
            int kq = s * 2 + lh;
            f16x8 af[2], bfr[2];
            #pragma unroll
            for (int mt = 0; mt < 2; ++mt)
                af[mt] = *reinterpret_cast<const f16x8*>(
                    &As[(size_t)(kq * 128 + wm * 64 + mt * 32 + l31) * 8]);
            #pragma unroll
            for (int nt = 0; nt < 2; ++nt)
                bfr[nt] = *reinterpret_cast<const f16x8*>(
                    &Bs[(size_t)(kq * 128 + wn * 64 + nt * 32 + l31) * 8]);
            #pragma unroll
            for (int mt = 0; mt < 2; ++mt)
                #pragma unroll
                for (int nt = 0; nt < 2; ++nt)
                    acc[mt][nt] = __builtin_amdgcn_mfma_f32_32x32x16_f16(af[mt], bfr[nt], acc[mt][nt], 0, 0, 0);
        }
        __syncthreads();
    }

    int b0 = bblk * 128;
    int c = nblk * 64 + wn * 32 + l31;   // complex m-col (0..319)
    #pragma unroll
    for (int mt = 0; mt < 2; ++mt) {
        #pragma unroll
        for (int reg = 0; reg < 16; ++reg) {
            int row = b0 + wm * 64 + mt * 32 + ((reg & 3) + 8 * (reg >> 2) + 4 * lh);
            errU[swzA2(row, c)] =
                (unsigned)f16bits(acc[mt][0][reg]) | ((unsigned)f16bits(acc[mt][1][reg]) << 16);
        }
    }
}

// ---------------- GEMM2: z = w + e'*(-step*conj(phi)) + rph; shrink; store (K=640) ------
__global__ __launch_bounds__(256, 2) void gemm_w_kernel(
    const _Float16* __restrict__ errF, const _Float16* __restrict__ B2,
    const _Float16* __restrict__ wfi, unsigned int* __restrict__ wfo,
    const unsigned int* __restrict__ rph16,
    const float* __restrict__ sc, float* __restrict__ out, int last) {
    __shared__ _Float16 As[8192];
    __shared__ _Float16 Bs[8192];
    int tid = threadIdx.x;
    int lane = tid & 63, wv = tid >> 6;
    int wm = wv & 1, wn = wv >> 1;
    int bblk = blockIdx.x, nblk = blockIdx.y;
    int l31 = lane & 31, lh = lane >> 5;

    f32x16 acc[2][2] = {};

    for (int kt = 0; kt < 10; ++kt) {
        #pragma unroll
        for (int c = 0; c < 4; ++c) {
            int u = c * 256 + tid;
            const char* ga = (const char*)errF + (((size_t)(bblk * 10 + kt)) * 1024 + u) * 16;
            load_lds16(ga, &As[(size_t)(c * 256 + wv * 64) * 8]);
            const char* gb = (const char*)B2 + (((size_t)(nblk * 10 + kt)) * 1024 + u) * 16;
            load_lds16(gb, &Bs[(size_t)(c * 256 + wv * 64) * 8]);
        }
        __syncthreads();
        #pragma unroll
        for (int s = 0; s < 4; ++s) {
            int kq = s * 2 + lh;
            f16x8 af[2], bfr[2];
            #pragma unroll
            for (int mt = 0; mt < 2; ++mt)
                af[mt] = *reinterpret_cast<const f16x8*>(
                    &As[(size_t)(kq * 128 + wm * 64 + mt * 32 + l31) * 8]);
            #pragma unroll
            for (int nt = 0; nt < 2; ++nt)
                bfr[nt] = *reinterpret_cast<const f16x8*>(
                    &Bs[(size_t)(kq * 128 + wn * 64 + nt * 32 + l31) * 8]);
            #pragma unroll
            for (int mt = 0; mt < 2; ++mt)
                #pragma unroll
                for (int nt = 0; nt < 2; ++nt)
                    acc[mt][nt] = __builtin_amdgcn_mfma_f32_32x32x16_f16(af[mt], bfr[nt], acc[mt][nt], 0, 0, 0);
        }
        __syncthreads();
    }

    float thr = sc[1];
    int b0 = bblk * 128;
    int c = nblk * 64 + wn * 32 + l31;   // complex n-col
    const unsigned int* wfin = (const unsigned int*)wfi;
    #pragma unroll
    for (int mt = 0; mt < 2; ++mt) {
        #pragma unroll
        for (int reg = 0; reg < 16; ++reg) {
            int row = b0 + wm * 64 + mt * 32 + ((reg & 3) + 8 * (reg >> 2) + 4 * lh);
            unsigned int wu = wfin[swzA(row, c)];
            unsigned int ru = rph16[(size_t)row * NCP + c];
            float zr = f16lo(wu) + acc[mt][0][reg] + f16lo(ru);
            float zi = f16hi(wu) + acc[mt][1][reg] + f16hi(ru);
            float mag = sqrtf(zr * zr + zi * zi);
            float nm = mag - thr;
            float f = (nm > 0.f) ? (nm / mag) : 0.f;
            wfo[swzA(row, c)] = (unsigned)f16bits(zr * f) | ((unsigned)f16bits(zi * f) << 16);
            if (last && c < Nn) out[(size_t)row * Nn + c] = fmaxf(nm, 0.f);
        }
    }
}

extern "C" void kernel_launch(void* const* d_in, const int* in_sizes, int n_in,
                              void* d_out, int out_size, void* d_ws, size_t ws_size,
                              hipStream_t stream) {
    const float* rr = (const float*)d_in[0];
    const float* ri = (const float*)d_in[1];
    const float* pr = (const float*)d_in[2];
    const float* pi = (const float*)d_in[3];
    float* out = (float*)d_out;

    char* ws = (char*)d_ws;
    size_t off = 0;
    _Float16* wf0 = (_Float16*)(ws + off); off += (size_t)Bb * KA * sizeof(_Float16);   // 16 MB
    _Float16* wf1 = (_Float16*)(ws + off); off += (size_t)Bb * KA * sizeof(_Float16);   // 16 MB
    _Float16* B1  = (_Float16*)(ws + off); off += (size_t)640 * 2048 * sizeof(_Float16);  // 2.6 MB
    _Float16* B2  = (_Float16*)(ws + off); off += (size_t)2048 * 640 * sizeof(_Float16);  // 2.6 MB
    _Float16* errF = (_Float16*)(ws + off); off += (size_t)Bb * 640 * sizeof(_Float16);   // 5.2 MB
    unsigned int* rph16 = (unsigned int*)(ws + off); off += (size_t)Bb * NCP * 4;       // 16 MB
    float2* G = (float2*)(ws + off);     off += (size_t)Mm * Mm * sizeof(float2);
    float2* H1 = (float2*)(ws + off);    off += (size_t)Mm * Mm * sizeof(float2);
    float2* H2 = (float2*)(ws + off);    off += (size_t)Mm * Mm * sizeof(float2);
    float* slots = (float*)(ws + off);   off += 64 * sizeof(float);
    float* sc = slots + 32;

    (void)hipMemsetAsync(wf0, 0, (size_t)Bb * KA * sizeof(_Float16), stream);
    (void)hipMemsetAsync(B1, 0, (size_t)640 * 2048 * sizeof(_Float16), stream);
    (void)hipMemsetAsync(B2, 0, (size_t)2048 * 640 * sizeof(_Float16), stream);
    (void)hipMemsetAsync(slots, 0, 64 * sizeof(float), stream);

    // spectral norm chain on G (306x306): G -> normalize+square x KSQ -> Rayleigh
    gram_kernel<<<dim3(20, 20), dim3(16, 16), 0, stream>>>(pr, pi, G);
    float2* bufs[2] = { H1, H2 };
    const float2* src = G;
    for (int s = 0; s < KSQ; ++s) {
        frob_kernel<<<128, 256, 0, stream>>>(src, slots + s, Mm * Mm);
        float2* dst = bufs[s & 1];
        (void)hipMemsetAsync(dst, 0, (size_t)Mm * Mm * sizeof(float2), stream);
        sqmm_kernel<<<dim3(10, 10, 4), dim3(16, 16), 0, stream>>>(src, dst, slots + s);
        src = dst;
    }
    rayleigh_kernel<<<1, 320, 0, stream>>>(src, G, sc);

    // precompute: phi packs (elementwise) and f16 step*rphi
    ppack_kernel<<<dim3((Nn + 255) / 256, Mm), 256, 0, stream>>>(
        pr, pi, (unsigned int*)B1, (unsigned int*)B2, sc);
    rphi_kernel<<<dim3(64, 16), 256, 0, stream>>>(rr, ri, pr, pi, rph16, sc);

    // ISTA main loop: two factored MFMA GEMMs per iteration, f16 state ping-pong
    _Float16* wbuf[2] = { wf0, wf1 };
    for (int it = 0; it < ITERS; ++it) {
        gemm_e_kernel<<<dim3(32, 5), 256, 0, stream>>>(
            wbuf[it & 1], B1, (unsigned int*)errF);
        gemm_w_kernel<<<dim3(32, 16), 256, 0, stream>>>(
            errF, B2, wbuf[it & 1], (unsigned int*)wbuf[(it + 1) & 1], rph16, sc, out,
            it == ITERS - 1 ? 1 : 0);
    }
}

// Round 9
// 3105.989 us; speedup vs baseline: 1.1506x; 1.1506x over previous
//
#include <hip/hip_runtime.h>
#include <math.h>

#define Bb 4096
#define Mm 306
#define Nn 984      // complex cols
#define NCP 1024    // padded complex cols
#define KA 2048     // w real k-cols (padded)
#define ITERS 50
#define KSQ 9       // squaring stages: G^(2^9) then Rayleigh

typedef _Float16 f16x8 __attribute__((ext_vector_type(8)));
typedef float f32x16 __attribute__((ext_vector_type(16)));

__device__ __forceinline__ void cmac(float2& c, const float2 a, const float2 b) {
    c.x = fmaf(a.x, b.x, c.x);
    c.x = fmaf(-a.y, b.y, c.x);
    c.y = fmaf(a.x, b.y, c.y);
    c.y = fmaf(a.y, b.x, c.y);
}

__device__ __forceinline__ unsigned short f16bits(float v) {
    union { _Float16 h; unsigned short u; } cv;
    cv.h = (_Float16)v;
    return cv.u;
}
__device__ __forceinline__ float f16lo(unsigned int u) {
    union { unsigned short s; _Float16 h; } cv; cv.s = (unsigned short)(u & 0xffffu);
    return (float)cv.h;
}
__device__ __forceinline__ float f16hi(unsigned int u) {
    union { unsigned short s; _Float16 h; } cv; cv.s = (unsigned short)(u >> 16);
    return (float)cv.h;
}

__device__ __forceinline__ void load_lds16(const void* g, void* l) {
    __builtin_amdgcn_global_load_lds((const __attribute__((address_space(1))) void*)g,
                                     (__attribute__((address_space(3))) void*)l, 16, 0, 0);
}

// ---- swizzled uint (4B) index, w/A operand (K=2048: 32 ktiles), (row b, complex col c) --
__device__ __forceinline__ size_t swzA(int b, int c) {
    return ((size_t)(((b >> 7) * 32 + (c >> 5)) * 1024 + ((c >> 2) & 7) * 128 + (b & 127))) * 4 + (c & 3);
}
// ---- B operand (Q op, K=2048: 32 ktiles), (row jr, uint col q) ----
__device__ __forceinline__ size_t swzB(int jr, int q) {
    return ((size_t)(((jr >> 7) * 32 + (q >> 5)) * 1024 + ((q >> 2) & 7) * 128 + (jr & 127))) * 4 + (q & 3);
}
// ---- A2 operand (r pack, K=640: 10 ktiles), (row b, complex col c<320) ----
__device__ __forceinline__ size_t swzA2(int b, int c) {
    return ((size_t)(((b >> 7) * 10 + (c >> 5)) * 1024 + ((c >> 2) & 7) * 128 + (b & 127))) * 4 + (c & 3);
}
// ---- B2 operand (-step*conj(phi) pack, K=640: 10 ktiles), (row jr, uint col q<320) ----
__device__ __forceinline__ size_t swzB2(int jr, int q) {
    return ((size_t)(((jr >> 7) * 10 + (q >> 5)) * 1024 + ((q >> 2) & 7) * 128 + (jr & 127))) * 4 + (q & 3);
}

// ---------------- G = phi * phi^H  (306x306 complex) ----------------
__global__ void gram_kernel(const float* __restrict__ pr, const float* __restrict__ pi,
                            float2* __restrict__ G) {
    int j = blockIdx.x * 16 + threadIdx.x;
    int i = blockIdx.y * 16 + threadIdx.y;
    if (i >= Mm || j >= Mm) return;
    const float* pri = pr + (size_t)i * Nn;
    const float* pii = pi + (size_t)i * Nn;
    const float* prj = pr + (size_t)j * Nn;
    const float* pij = pi + (size_t)j * Nn;
    float ar = 0.f, ai = 0.f;
    for (int n = 0; n < Nn; ++n) {
        float xr = pri[n], xi = pii[n], yr = prj[n], yi = pij[n];
        ar = fmaf(xr, yr, ar); ar = fmaf(xi, yi, ar);
        ai = fmaf(xi, yr, ai); ai = fmaf(-xr, yi, ai);
    }
    G[i * Mm + j] = make_float2(ar, ai);
}

// ---------------- Frobenius^2 reduction ----------------
__global__ void frob_kernel(const float2* __restrict__ H, float* __restrict__ slot, int n) {
    int idx = blockIdx.x * blockDim.x + threadIdx.x;
    int stride = gridDim.x * blockDim.x;
    float s = 0.f;
    for (int i = idx; i < n; i += stride) {
        float2 v = H[i];
        s = fmaf(v.x, v.x, s);
        s = fmaf(v.y, v.y, s);
    }
    #pragma unroll
    for (int o = 32; o > 0; o >>= 1) s += __shfl_down(s, o, 64);
    __shared__ float wsum[4];
    int lane = threadIdx.x & 63, wv = threadIdx.x >> 6;
    if (lane == 0) wsum[wv] = s;
    __syncthreads();
    if (threadIdx.x == 0) atomicAdd(slot, wsum[0] + wsum[1] + wsum[2] + wsum[3]);
}

// ---------------- C += (A/||A||_F)^2 partial (split-K, C pre-zeroed) ----------------
__global__ void sqmm_kernel(const float2* __restrict__ A, float2* __restrict__ C,
                            const float* __restrict__ fslot) {
    __shared__ float2 As[32][33];
    __shared__ float2 Bs[32][33];
    float inv = 1.0f / fslot[0];
    int tx = threadIdx.x, ty = threadIdx.y;
    int t = ty * 16 + tx;
    int r0 = blockIdx.y * 32, c0 = blockIdx.x * 32;
    int zs = blockIdx.z * 80;
    int ze = zs + 80 < Mm ? zs + 80 : Mm;
    float2 acc[2][2] = {};
    for (int k0 = zs; k0 < ze; k0 += 32) {
        #pragma unroll
        for (int i = 0; i < 4; ++i) {
            int idx = t + i * 256;
            int rr = idx >> 5, cc = idx & 31;
            int gr = r0 + rr, gk = k0 + cc;
            As[rr][cc] = (gr < Mm && gk < ze) ? A[gr * Mm + gk] : make_float2(0.f, 0.f);
            int gk2 = k0 + rr, gc = c0 + cc;
            Bs[rr][cc] = (gk2 < ze && gc < Mm) ? A[gk2 * Mm + gc] : make_float2(0.f, 0.f);
        }
        __syncthreads();
        #pragma unroll 8
        for (int kk = 0; kk < 32; ++kk) {
            float2 a0 = As[ty * 2][kk], a1 = As[ty * 2 + 1][kk];
            float2 b0 = Bs[kk][tx * 2], b1 = Bs[kk][tx * 2 + 1];
            cmac(acc[0][0], a0, b0); cmac(acc[0][1], a0, b1);
            cmac(acc[1][0], a1, b0); cmac(acc[1][1], a1, b1);
        }
        __syncthreads();
    }
    #pragma unroll
    for (int i = 0; i < 2; ++i) {
        int gr = r0 + ty * 2 + i;
        #pragma unroll
        for (int j = 0; j < 2; ++j) {
            int gc = c0 + tx * 2 + j;
            if (gr < Mm && gc < Mm) {
                atomicAdd(&C[gr * Mm + gc].x, acc[i][j].x * inv);
                atomicAdd(&C[gr * Mm + gc].y, acc[i][j].y * inv);
            }
        }
    }
}

// ---------------- Rayleigh: lambda = v^H G v / v^H v, v = H*ones ----------------
__global__ void rayleigh_kernel(const float2* __restrict__ H, const float2* __restrict__ G,
                                float* __restrict__ sc) {
    __shared__ float2 v[Mm];
    __shared__ float rn[320], rd[320];
    int t = threadIdx.x;
    if (t < Mm) {
        float2 s = make_float2(0.f, 0.f);
        for (int j = 0; j < Mm; ++j) { float2 h = H[t * Mm + j]; s.x += h.x; s.y += h.y; }
        v[t] = s;
    }
    __syncthreads();
    float num = 0.f, den = 0.f;
    if (t < Mm) {
        float2 u = make_float2(0.f, 0.f);
        for (int k = 0; k < Mm; ++k) {
            float2 g = G[k * Mm + t];
            float2 vk = v[k];
            u.x = fmaf(g.x, vk.x, u.x); u.x = fmaf(g.y, vk.y, u.x);
            u.y = fmaf(g.x, vk.y, u.y); u.y = fmaf(-g.y, vk.x, u.y);
        }
        float2 vt = v[t];
        num = vt.x * u.x + vt.y * u.y;
        den = vt.x * vt.x + vt.y * vt.y;
    }
    rn[t] = num; rd[t] = den;
    __syncthreads();
    if (t == 0) {
        float sn = 0.f, sd = 0.f;
        for (int i = 0; i < 320; ++i) { sn += rn[i]; sd += rd[i]; }
        float lam = sn / sd;
        float step = 1.0f / lam;
        sc[0] = step;
        sc[1] = 0.1f * step;
    }
}

// ---------------- qpack: M = -step*Q (Q[n][c] = sum_m phi[m][n]*conj(phi[m][c]))
// -> swizzled single-limb f16. Row jr = (c>>5)*64 + (c&31) [Re], +32 [Im]; uint col q = n
__global__ void qpack_kernel(const float* __restrict__ pr, const float* __restrict__ pi,
                             unsigned int* __restrict__ Bu, const float* __restrict__ sc) {
    __shared__ float2 Pn[16][33];
    __shared__ float2 Pc[16][33];
    float nstep = -sc[0];
    int t = threadIdx.x;
    int tx = t & 15, ty = t >> 4;
    int n0 = blockIdx.x * 32, c0 = blockIdx.y * 32;
    float2 q[2][2] = {};
    for (int m0 = 0; m0 < Mm; m0 += 16) {
        #pragma unroll
        for (int rep = 0; rep < 2; ++rep) {
            int idx = t + rep * 256;
            int mm = idx >> 5, col = idx & 31;
            int gm = m0 + mm;
            float2 a = make_float2(0.f, 0.f), b = make_float2(0.f, 0.f);
            if (gm < Mm) {
                if (n0 + col < Nn) a = make_float2(pr[(size_t)gm * Nn + n0 + col], pi[(size_t)gm * Nn + n0 + col]);
                if (c0 + col < Nn) b = make_float2(pr[(size_t)gm * Nn + c0 + col], pi[(size_t)gm * Nn + c0 + col]);
            }
            Pn[mm][col] = a; Pc[mm][col] = b;
        }
        __syncthreads();
        #pragma unroll
        for (int mm = 0; mm < 16; ++mm) {
            float2 a0 = Pn[mm][ty * 2], a1 = Pn[mm][ty * 2 + 1];
            float2 b0 = Pc[mm][tx * 2], b1 = Pc[mm][tx * 2 + 1];
            // q += a * conj(b)
            #define QMAC(qq, aa, bb) \
                qq.x = fmaf(aa.x, bb.x, qq.x); qq.x = fmaf(aa.y, bb.y, qq.x); \
                qq.y = fmaf(aa.y, bb.x, qq.y); qq.y = fmaf(-aa.x, bb.y, qq.y);
            QMAC(q[0][0], a0, b0) QMAC(q[0][1], a0, b1)
            QMAC(q[1][0], a1, b0) QMAC(q[1][1], a1, b1)
            #undef QMAC
        }
        __syncthreads();
    }
    #pragma unroll
    for (int i = 0; i < 2; ++i) {
        int n = n0 + ty * 2 + i;
        #pragma unroll
        for (int j = 0; j < 2; ++j) {
            int c = c0 + tx * 2 + j;
            if (n < Nn && c < Nn) {
                float MR = nstep * q[i][j].x, MI = nstep * q[i][j].y;
                unsigned short hR = f16bits(MR);
                unsigned short hI = f16bits(MI);
                unsigned short nhI = hI ^ 0x8000u;
                int jr = ((c >> 5) * 64) + (c & 31);
                Bu[swzB(jr, n)]      = (unsigned)hR | ((unsigned)nhI << 16);  // Re row
                Bu[swzB(jr + 32, n)] = (unsigned)hI | ((unsigned)hR << 16);   // Im row
            }
        }
    }
}

// ---------------- rpack: r -> f16 pairs in A2 layout (K=640) ----------------
__global__ void rpack_kernel(const float* __restrict__ rr, const float* __restrict__ ri,
                             unsigned int* __restrict__ rp16) {
    int b = blockIdx.x * 256 + threadIdx.x;
    int m = blockIdx.y;
    rp16[swzA2(b, m)] = (unsigned)f16bits(rr[(size_t)b * Mm + m]) |
                        ((unsigned)f16bits(ri[(size_t)b * Mm + m]) << 16);
}

// ---------------- ppack2: B2 = -step*conj(phi) pack, K=640 layout ----------------
__global__ void ppack2_kernel(const float* __restrict__ pr, const float* __restrict__ pi,
                              unsigned int* __restrict__ B2u, const float* __restrict__ sc) {
    int n = blockIdx.x * 256 + threadIdx.x;
    int m = blockIdx.y;
    if (n >= Nn) return;
    float s = sc[0];
    float xr = pr[(size_t)m * Nn + n], xi = pi[(size_t)m * Nn + n];
    unsigned short x = f16bits(-s * xr), y = f16bits(-s * xi);
    int jr2 = ((n >> 5) * 64) + (n & 31);
    B2u[swzB2(jr2, m)]      = (unsigned)x | ((unsigned)y << 16);
    B2u[swzB2(jr2 + 32, m)] = (unsigned)(y ^ 0x8000u) | ((unsigned)x << 16);
}

// ---------------- rphi_mfma: rph16 = -(rpack · B2) = f16(step * r * conj(phi)) ----------
__global__ __launch_bounds__(256, 2) void rphi_mfma_kernel(
    const _Float16* __restrict__ rp16, const _Float16* __restrict__ B2,
    unsigned int* __restrict__ rph16) {
    __shared__ _Float16 As[8192];
    __shared__ _Float16 Bs[8192];
    int tid = threadIdx.x;
    int lane = tid & 63, wv = tid >> 6;
    int wm = wv & 1, wn = wv >> 1;
    int bblk = blockIdx.x, nblk = blockIdx.y;
    int l31 = lane & 31, lh = lane >> 5;

    f32x16 acc[2][2] = {};

    for (int kt = 0; kt < 10; ++kt) {
        #pragma unroll
        for (int c = 0; c < 4; ++c) {
            int u = c * 256 + tid;
            const char* ga = (const char*)rp16 + (((size_t)(bblk * 10 + kt)) * 1024 + u) * 16;
            load_lds16(ga, &As[(size_t)(c * 256 + wv * 64) * 8]);
            const char* gb = (const char*)B2 + (((size_t)(nblk * 10 + kt)) * 1024 + u) * 16;
            load_lds16(gb, &Bs[(size_t)(c * 256 + wv * 64) * 8]);
        }
        __syncthreads();
        #pragma unroll
        for (int s = 0; s < 4; ++s) {
            int kq = s * 2 + lh;
            f16x8 af[2], bfr[2];
            #pragma unroll
            for (int mt = 0; mt < 2; ++mt)
                af[mt] = *reinterpret_cast<const f16x8*>(
                    &As[(size_t)(kq * 128 + wm * 64 + mt * 32 + l31) * 8]);
            #pragma unroll
            for (int nt = 0; nt < 2; ++nt)
                bfr[nt] = *reinterpret_cast<const f16x8*>(
                    &Bs[(size_t)(kq * 128 + wn * 64 + nt * 32 + l31) * 8]);
            #pragma unroll
            for (int mt = 0; mt < 2; ++mt)
                #pragma unroll
                for (int nt = 0; nt < 2; ++nt)
                    acc[mt][nt] = __builtin_amdgcn_mfma_f32_32x32x16_f16(af[mt], bfr[nt], acc[mt][nt], 0, 0, 0);
        }
        __syncthreads();
    }

    int b0 = bblk * 128;
    int c = nblk * 64 + wn * 32 + l31;
    #pragma unroll
    for (int mt = 0; mt < 2; ++mt) {
        #pragma unroll
        for (int reg = 0; reg < 16; ++reg) {
            int row = b0 + wm * 64 + mt * 32 + ((reg & 3) + 8 * (reg >> 2) + 4 * lh);
            rph16[(size_t)row * NCP + c] =
                (unsigned)f16bits(-acc[mt][0][reg]) | ((unsigned)f16bits(-acc[mt][1][reg]) << 16);
        }
    }
}

// ---------------- main ISTA iteration: 32x32x16 f16 MFMA, f16-only state ----------------
// XCD swizzle: id%8 = XCD -> nblk = id&15 (2 operator columns per XCD, L2-resident)
__global__ __launch_bounds__(256, 2) void ista7_kernel(
    const _Float16* __restrict__ wfi, const _Float16* __restrict__ Bq,
    unsigned int* __restrict__ wfo,
    const unsigned int* __restrict__ rph16,
    const float* __restrict__ sc, float* __restrict__ out, int last) {
    __shared__ _Float16 As[8192];   // w tile: [kq 0..7][m 0..127] 16B units
    __shared__ _Float16 Bs[8192];   // operator tile
    int tid = threadIdx.x;
    int lane = tid & 63, wv = tid >> 6;
    int wm = wv & 1, wn = wv >> 1;
    int id = blockIdx.x;
    int bblk = id >> 4;            // 0..31
    int nblk = id & 15;            // 0..15 ; XCD = id&7 -> nblk in {x, x+8}
    int l31 = lane & 31, lh = lane >> 5;

    f32x16 acc[2][2] = {};   // [mt][nt: 0=Re,1=Im]

    for (int kt = 0; kt < 32; ++kt) {
        #pragma unroll
        for (int c = 0; c < 4; ++c) {
            int u = c * 256 + tid;
            const char* ga = (const char*)wfi + (((size_t)(bblk * 32 + kt)) * 1024 + u) * 16;
            load_lds16(ga, &As[(size_t)(c * 256 + wv * 64) * 8]);
            const char* gb = (const char*)Bq + (((size_t)(nblk * 32 + kt)) * 1024 + u) * 16;
            load_lds16(gb, &Bs[(size_t)(c * 256 + wv * 64) * 8]);
        }
        __syncthreads();
        #pragma unroll
        for (int s = 0; s < 4; ++s) {
            int kq = s * 2 + lh;
            f16x8 af[2], bfr[2];
            #pragma unroll
            for (int mt = 0; mt < 2; ++mt)
                af[mt] = *reinterpret_cast<const f16x8*>(
                    &As[(size_t)(kq * 128 + wm * 64 + mt * 32 + l31) * 8]);
            #pragma unroll
            for (int nt = 0; nt < 2; ++nt)
                bfr[nt] = *reinterpret_cast<const f16x8*>(
                    &Bs[(size_t)(kq * 128 + wn * 64 + nt * 32 + l31) * 8]);
            #pragma unroll
            for (int mt = 0; mt < 2; ++mt)
                #pragma unroll
                for (int nt = 0; nt < 2; ++nt)
                    acc[mt][nt] = __builtin_amdgcn_mfma_f32_32x32x16_f16(af[mt], bfr[nt], acc[mt][nt], 0, 0, 0);
        }
        __syncthreads();
    }

    float thr = sc[1];
    int b0 = bblk * 128;
    int c = nblk * 64 + wn * 32 + l31;   // complex col for this lane
    const unsigned int* wfin = (const unsigned int*)wfi;
    #pragma unroll
    for (int mt = 0; mt < 2; ++mt) {
        #pragma unroll
        for (int reg = 0; reg < 16; ++reg) {
            int row = b0 + wm * 64 + mt * 32 + ((reg & 3) + 8 * (reg >> 2) + 4 * lh);
            unsigned int wu = wfin[swzA(row, c)];
            unsigned int ru = rph16[(size_t)row * NCP + c];
            float zr = f16lo(wu) + acc[mt][0][reg] + f16lo(ru);
            float zi = f16hi(wu) + acc[mt][1][reg] + f16hi(ru);
            float mag = sqrtf(zr * zr + zi * zi);
            float nm = mag - thr;
            float f = (nm > 0.f) ? (nm / mag) : 0.f;
            wfo[swzA(row, c)] = (unsigned)f16bits(zr * f) | ((unsigned)f16bits(zi * f) << 16);
            if (last && c < Nn) out[(size_t)row * Nn + c] = fmaxf(nm, 0.f);
        }
    }
}

extern "C" void kernel_launch(void* const* d_in, const int* in_sizes, int n_in,
                              void* d_out, int out_size, void* d_ws, size_t ws_size,
                              hipStream_t stream) {
    const float* rr = (const float*)d_in[0];
    const float* ri = (const float*)d_in[1];
    const float* pr = (const float*)d_in[2];
    const float* pi = (const float*)d_in[3];
    float* out = (float*)d_out;

    char* ws = (char*)d_ws;
    size_t off = 0;
    _Float16* wf0 = (_Float16*)(ws + off); off += (size_t)Bb * KA * sizeof(_Float16);   // 16 MB
    _Float16* wf1 = (_Float16*)(ws + off); off += (size_t)Bb * KA * sizeof(_Float16);   // 16 MB
    _Float16* Bq  = (_Float16*)(ws + off); off += (size_t)2048 * 2048 * sizeof(_Float16); // 8 MB
    unsigned int* rph16 = (unsigned int*)(ws + off); off += (size_t)Bb * NCP * 4;       // 16 MB
    _Float16* rp16 = (_Float16*)(ws + off); off += (size_t)Bb * 640 * sizeof(_Float16);   // 5.2 MB
    _Float16* B2  = (_Float16*)(ws + off); off += (size_t)2048 * 640 * sizeof(_Float16);  // 2.6 MB
    float2* G = (float2*)(ws + off);     off += (size_t)Mm * Mm * sizeof(float2);
    float2* H1 = (float2*)(ws + off);    off += (size_t)Mm * Mm * sizeof(float2);
    float2* H2 = (float2*)(ws + off);    off += (size_t)Mm * Mm * sizeof(float2);
    float* slots = (float*)(ws + off);   off += 64 * sizeof(float);
    float* sc = slots + 32;

    (void)hipMemsetAsync(wf0, 0, (size_t)Bb * KA * sizeof(_Float16), stream);
    (void)hipMemsetAsync(Bq, 0, (size_t)2048 * 2048 * sizeof(_Float16), stream);
    (void)hipMemsetAsync(rp16, 0, (size_t)Bb * 640 * sizeof(_Float16), stream);
    (void)hipMemsetAsync(B2, 0, (size_t)2048 * 640 * sizeof(_Float16), stream);
    (void)hipMemsetAsync(slots, 0, 64 * sizeof(float), stream);

    // spectral norm chain on G (306x306): G -> normalize+square x KSQ -> Rayleigh
    gram_kernel<<<dim3(20, 20), dim3(16, 16), 0, stream>>>(pr, pi, G);
    float2* bufs[2] = { H1, H2 };
    const float2* src = G;
    for (int s = 0; s < KSQ; ++s) {
        frob_kernel<<<128, 256, 0, stream>>>(src, slots + s, Mm * Mm);
        float2* dst = bufs[s & 1];
        (void)hipMemsetAsync(dst, 0, (size_t)Mm * Mm * sizeof(float2), stream);
        sqmm_kernel<<<dim3(10, 10, 4), dim3(16, 16), 0, stream>>>(src, dst, slots + s);
        src = dst;
    }
    rayleigh_kernel<<<1, 320, 0, stream>>>(src, G, sc);

    // precompute: packed operator (-step*Q f16), r pack, -step*conj(phi) pack, rphi MFMA
    qpack_kernel<<<dim3(31, 31), 256, 0, stream>>>(pr, pi, (unsigned int*)Bq, sc);
    rpack_kernel<<<dim3(16, Mm), 256, 0, stream>>>(rr, ri, (unsigned int*)rp16);
    ppack2_kernel<<<dim3(4, Mm), 256, 0, stream>>>(pr, pi, (unsigned int*)B2, sc);
    rphi_mfma_kernel<<<dim3(32, 16), 256, 0, stream>>>(rp16, B2, rph16);

    // ISTA main loop: one fused MFMA GEMM per iteration, f16 state ping-pong
    _Float16* wbuf[2] = { wf0, wf1 };
    for (int it = 0; it < ITERS; ++it) {
        ista7_kernel<<<512, 256, 0, stream>>>(
            wbuf[it & 1], Bq, (unsigned int*)wbuf[(it + 1) & 1], rph16, sc, out,
            it == ITERS - 1 ? 1 : 0);
    }
}